// Round 8
// baseline (1309.078 us; speedup 1.0000x reference)
//
#include <hip/hip_runtime.h>
#include <math.h>

typedef __attribute__((ext_vector_type(2))) float f32x2;

#define MAX_DELAY 128
#define INPUT 64
#define HIDDEN 128
#define HALF 64
#define OUT 64
#define BATCH 32
#define T 128
#define OUT_LEN 64
#define NTHR 1024   // two batch elements per block, 512 threads each

static __device__ __forceinline__ f32x2 splat2(float v) { f32x2 r; r.x = v; r.y = v; return r; }

// DPP cross-lane (1-cycle VALU).
template <int CTRL>
static __device__ __forceinline__ float dpp_movf(float v) {
    return __int_as_float(__builtin_amdgcn_update_dpp(
        0, __float_as_int(v), CTRL, 0xF, 0xF, true));
}
#define DPP_XOR1 0xB1  // quad_perm [1,0,3,2]
#define DPP_XOR2 0x4E  // quad_perm [2,3,0,1]
#define DPP_ROT1 0x39  // quad_perm [1,2,3,0]
#define DPP_MIR8 0x141 // row_half_mirror

// R5 body (best known: uniform waves, 3 barriers, DPP reduces, quad-local
// tau/mem, register delay-buffer) x TWO batch elements per block.
// half = tid>>9 selects the batch element; each half runs the identical
// phase schedule on its own LDS arrays, so the shared block barrier stays
// balanced, while each SIMD hosts 2 half-0 + 2 half-1 waves -> the two
// independent dependency chains fill each other's post-barrier bubbles.
__global__ __launch_bounds__(NTHR)
void delayrnn_kernel(
    const float* __restrict__ x,        // (B, T, INPUT)
    const int*   __restrict__ lengths,  // (B)
    const float* __restrict__ Wm,       // (INPUT+HIDDEN, HIDDEN)
    const float* __restrict__ bm,       // (HIDDEN)
    const float* __restrict__ W1,       // (HIDDEN, HALF)
    const float* __restrict__ b1,       // (HALF)
    const float* __restrict__ W2,       // (HALF, 2*HIDDEN)
    const float* __restrict__ b2,       // (2*HIDDEN)
    const float* __restrict__ Wo,       // (HIDDEN, OUT)
    const float* __restrict__ bo,       // (OUT)
    float* __restrict__ out)            // (B, OUT_LEN, OUT)
{
    const int half = threadIdx.x >> 9;        // which batch element of the pair
    const int tid  = threadIdx.x & 511;       // thread id within the half
    const int b    = blockIdx.x * 2 + half;
    const int len  = lengths[b];
    const int total = len + OUT_LEN;
    const int lenA = lengths[blockIdx.x * 2];
    const int lenB = lengths[blockIdx.x * 2 + 1];
    const int tmax = ((lenA > lenB) ? lenA : lenB) + OUT_LEN;

    // role mappings (quad/8-aligned within the wave; tid%64 == lane)
    const int h  = tid >> 2, q  = tid & 3;   // channel quad
    const int qq = q & 1,    qh = q >> 1;    // tau/mem roles
    const int k1 = tid >> 3, r1 = tid & 7;   // h1 groups
    const int co = tid >> 3, ro = tid & 7;   // out-proj groups

    // ---- weights -> registers (packed along K) ----
    f32x2 wm2[24];
#pragma unroll
    for (int j = 0; j < 24; ++j) {
        wm2[j].x = Wm[(q * 48 + 2 * j)     * HIDDEN + h];
        wm2[j].y = Wm[(q * 48 + 2 * j + 1) * HIDDEN + h];
    }
    f32x2 w12[8];
#pragma unroll
    for (int j = 0; j < 8; ++j) {
        w12[j].x = W1[(r1 * 16 + 2 * j)     * HALF + k1];
        w12[j].y = W1[(r1 * 16 + 2 * j + 1) * HALF + k1];
    }
    const int c2 = h + 128 * qh;
    f32x2 w22[16];
#pragma unroll
    for (int j = 0; j < 16; ++j) {
        w22[j].x = W2[(qq * 32 + 2 * j)     * (2 * HIDDEN) + c2];
        w22[j].y = W2[(qq * 32 + 2 * j + 1) * (2 * HIDDEN) + c2];
    }
    f32x2 wo2[8];
#pragma unroll
    for (int j = 0; j < 8; ++j) {
        wo2[j].x = Wo[(ro * 16 + 2 * j)     * OUT + co];
        wo2[j].y = Wo[(ro * 16 + 2 * j + 1) * OUT + co];
    }
    const float bm_r = bm[h];
    const float b1_r = b1[k1];
    const float b2_r = b2[c2];
    const float bo_r = bo[co];

    // delay-buffer slice: channel h, delays q*32 .. q*32+31
    float buf[32];
#pragma unroll
    for (int d = 0; d < 32; ++d) buf[d] = 0.f;

    __shared__ float s_x[2][T * INPUT];       // 64 KB staged inputs
    __shared__ float s_v[2][INPUT + HIDDEN];  // [x_t | heads]
    __shared__ float s_msg[2][HIDDEN];
    __shared__ float s_h1[2][HALF];

    for (int idx = tid; idx < T * INPUT; idx += 512)
        s_x[half][idx] = x[b * T * INPUT + idx];
    if (tid < INPUT) s_v[half][tid] = (0 < len) ? x[b * T * INPUT + tid] : 0.f;
    if (tid >= INPUT && tid < INPUT + HIDDEN) s_v[half][tid] = 0.f;  // heads
    __syncthreads();                                                  // B1

    const float ivb = (float)q * 0.25f;

    for (int i = 0; i < tmax; ++i) {
        // ---- msg[h] = tanh(v . Wm + bm), allreduced over the quad ----
        const f32x2* v2 = (const f32x2*)(s_v[half] + q * 48);
        f32x2 a0 = splat2(0.f), a1 = splat2(0.f), a2 = splat2(0.f), a3 = splat2(0.f);
#pragma unroll
        for (int j = 0; j < 24; j += 4) {
            a0 += wm2[j] * v2[j];         a1 += wm2[j + 1] * v2[j + 1];
            a2 += wm2[j + 2] * v2[j + 2]; a3 += wm2[j + 3] * v2[j + 3];
        }
        f32x2 aa = (a0 + a1) + (a2 + a3);
        float p = aa.x + aa.y;
        p += dpp_movf<DPP_XOR1>(p);
        p += dpp_movf<DPP_XOR2>(p);
        const float z  = p + bm_r;
        const float e2 = __expf(2.f * z);
        const float msg = 1.f - 2.f * __builtin_amdgcn_rcpf(e2 + 1.f);  // tanh
        if (q == 0) s_msg[half][h] = msg;
        __syncthreads();                            // B2

        // ---- h1[k1] = relu(msg . W1 + b1) ----
        const f32x2* m2 = (const f32x2*)(s_msg[half] + r1 * 16);
        f32x2 c0 = splat2(0.f), c1 = splat2(0.f);
#pragma unroll
        for (int j = 0; j < 8; j += 2) { c0 += w12[j] * m2[j]; c1 += w12[j + 1] * m2[j + 1]; }
        f32x2 cc = c0 + c1;
        float p1 = cc.x + cc.y;
        p1 += dpp_movf<DPP_XOR1>(p1);
        p1 += dpp_movf<DPP_XOR2>(p1);
        p1 += dpp_movf<DPP_MIR8>(p1);               // 8-lane allreduce
        if (r1 == 0) s_h1[half][k1] = fmaxf(p1 + b1_r, 0.f);
        __syncthreads();                            // B3

        // ---- tau/mem: quad-internal, fully in-register ----
        const f32x2* h2 = (const f32x2*)(s_h1[half] + qq * 32);
        f32x2 t0 = splat2(0.f), t1 = splat2(0.f);
#pragma unroll
        for (int j = 0; j < 16; j += 2) { t0 += w22[j] * h2[j]; t1 += w22[j + 1] * h2[j + 1]; }
        f32x2 tt = t0 + t1;
        float pt = tt.x + tt.y;
        pt += dpp_movf<DPP_XOR1>(pt);
        const float own = __builtin_amdgcn_rcpf(1.f + __expf(-(pt + b2_r)));
        const float oth = dpp_movf<DPP_XOR2>(own);
        const float tau_r = qh ? oth : own;
        const float mem_r = qh ? own : oth;

        // ---- blend: shift + interpolate (channel h, delays q*32+d) ----
        {
            float tail_in = dpp_movf<DPP_ROT1>(buf[0]);  // neighbor q+1's old head
            if (q == 3) tail_in = 0.f;
            const float taup = tau_r - ivb;
            const f32x2 tau2 = splat2(taup);
            const f32x2 mem2 = splat2(mem_r);
            const f32x2 m2m  = splat2(-2.f * mem_r);
            const f32x2 msg2 = splat2(msg);
#pragma unroll
            for (int mp = 0; mp < 16; ++mp) {
                const int d = 2 * mp;
                f32x2 nb;
                nb.x = buf[d + 1];
                nb.y = (mp < 15) ? buf[d + 2] : tail_in;
                f32x2 t;
                t.x = tau2.x - (float)d       * (1.f / MAX_DELAY);
                t.y = tau2.y - (float)(d + 1) * (1.f / MAX_DELAY);
                f32x2 a  = __builtin_elementwise_max(t, -t);
                f32x2 f1 = a * mem2 + m2m;
                f32x2 iw = a * f1 + mem2;
                f32x2 dd = msg2 - nb;
                f32x2 nv = iw * dd + nb;
                buf[d] = nv.x; buf[d + 1] = nv.y;
            }
        }
        if (q == 0) s_v[half][INPUT + h] = buf[0];  // head for next step's v

        // ---- decode out-projection (only within this half's range) ----
        if (i >= len && i < total) {
            const f32x2* mo2 = (const f32x2*)(s_msg[half] + ro * 16);
            f32x2 o0 = splat2(0.f), o1 = splat2(0.f);
#pragma unroll
            for (int j = 0; j < 8; j += 2) { o0 += wo2[j] * mo2[j]; o1 += wo2[j + 1] * mo2[j + 1]; }
            f32x2 oo = o0 + o1;
            float po = oo.x + oo.y;
            po += dpp_movf<DPP_XOR1>(po);
            po += dpp_movf<DPP_XOR2>(po);
            po += dpp_movf<DPP_MIR8>(po);
            if (ro == 0) out[(b * OUT_LEN + (i - len)) * OUT + co] = po + bo_r;
        }

        // ---- stage next x slice (zeros once past this half's encoder) ----
        if (tid < INPUT) {
            const int nx = i + 1;
            s_v[half][tid] = (nx < len) ? s_x[half][nx * INPUT + tid] : 0.f;
        }
        __syncthreads();                            // B1 (next iter)
    }
}

extern "C" void kernel_launch(void* const* d_in, const int* in_sizes, int n_in,
                              void* d_out, int out_size, void* d_ws, size_t ws_size,
                              hipStream_t stream) {
    const float* x       = (const float*)d_in[0];
    const int*   lengths = (const int*)  d_in[1];
    // d_in[2] = out_lengths scalar (compile-time 64)
    const float* Wm = (const float*)d_in[3];
    const float* bm = (const float*)d_in[4];
    const float* W1 = (const float*)d_in[5];
    const float* b1 = (const float*)d_in[6];
    const float* W2 = (const float*)d_in[7];
    const float* b2 = (const float*)d_in[8];
    const float* Wo = (const float*)d_in[9];
    const float* bo = (const float*)d_in[10];
    float* out = (float*)d_out;

    delayrnn_kernel<<<BATCH / 2, NTHR, 0, stream>>>(
        x, lengths, Wm, bm, W1, b1, W2, b2, Wo, bo, out);
}

// Round 9
// 472.085 us; speedup vs baseline: 2.7730x; 2.7730x over previous
//
#include <hip/hip_runtime.h>
#include <math.h>

typedef __attribute__((ext_vector_type(2))) float    f32x2;
typedef __attribute__((ext_vector_type(2))) _Float16 f16x2;

#define MAX_DELAY 128
#define INPUT 64
#define HIDDEN 128
#define HALF 64
#define OUT 64
#define BATCH 32
#define T 128
#define OUT_LEN 64
#define NTHR 512   // 2 batch elements per block, 256 threads each

static __device__ __forceinline__ f32x2 splat2(float v) { f32x2 r; r.x = v; r.y = v; return r; }
static __device__ __forceinline__ f16x2 mkh2(float a, float b) {
    f16x2 r; r.x = (_Float16)a; r.y = (_Float16)b; return r;
}

#if __has_builtin(__builtin_amdgcn_fdot2)
static __device__ __forceinline__ float fdot2(f16x2 w, f16x2 v, float c) {
    return __builtin_amdgcn_fdot2(w, v, c, false);
}
#else
static __device__ __forceinline__ float fdot2(f16x2 w, f16x2 v, float c) {
    return fmaf((float)w.y, (float)v.y, fmaf((float)w.x, (float)v.x, c));
}
#endif

// K/2 f16x2 elements, 4 independent accumulators (N multiple of 4).
template <int N>
static __device__ __forceinline__ float dot_h2(const f16x2* __restrict__ w,
                                               const f16x2* __restrict__ v) {
    float a0 = 0.f, a1 = 0.f, a2 = 0.f, a3 = 0.f;
#pragma unroll
    for (int j = 0; j < N; j += 4) {
        a0 = fdot2(w[j],     v[j],     a0);
        a1 = fdot2(w[j + 1], v[j + 1], a1);
        a2 = fdot2(w[j + 2], v[j + 2], a2);
        a3 = fdot2(w[j + 3], v[j + 3], a3);
    }
    return (a0 + a1) + (a2 + a3);
}

template <int CTRL>
static __device__ __forceinline__ float dpp_movf(float v) {
    return __int_as_float(__builtin_amdgcn_update_dpp(
        0, __float_as_int(v), CTRL, 0xF, 0xF, true));
}
#define DPP_XOR1 0xB1  // quad_perm [1,0,3,2]
#define DPP_XOR2 0x4E  // quad_perm [2,3,0,1]

// Two independent batch elements per 512-thread block (256 threads each).
// Waves 0-3 = half 0, waves 4-7 = half 1 -> each SIMD hosts one wave of each
// chain; the chains' post-barrier LDS/dependency stalls are filled by the
// other chain's issuable ALU, amortizing the per-phase latency 2x.
// Weights are f16-packed in registers (v_dot2_f32_f16, fp32 accumulate);
// activations cross LDS as f16. Delay buffer: 2 thr/channel x 64 delays in
// fp32 registers (R7-verified mapping). 3 barriers/step, R5 phase schedule.
__global__ __launch_bounds__(NTHR, 2)
void delayrnn_kernel(
    const float* __restrict__ x,        // (B, T, INPUT)
    const int*   __restrict__ lengths,  // (B)
    const float* __restrict__ Wm,       // (INPUT+HIDDEN, HIDDEN)
    const float* __restrict__ bm,       // (HIDDEN)
    const float* __restrict__ W1,       // (HIDDEN, HALF)
    const float* __restrict__ b1,       // (HALF)
    const float* __restrict__ W2,       // (HALF, 2*HIDDEN)
    const float* __restrict__ b2,       // (2*HIDDEN)
    const float* __restrict__ Wo,       // (HIDDEN, OUT)
    const float* __restrict__ bo,       // (OUT)
    float* __restrict__ out)            // (B, OUT_LEN, OUT)
{
    const int half = threadIdx.x >> 8;        // batch element within the pair
    const int u    = threadIdx.x & 255;       // thread id within the half
    const int blk  = blockIdx.x;
    const int b    = blk * 2 + half;
    const int len  = lengths[b];
    const int total = len + OUT_LEN;
    const int lenA = lengths[blk * 2], lenB = lengths[blk * 2 + 1];
    const int tmax = ((lenA > lenB) ? lenA : lenB) + OUT_LEN;

    // role mappings (all pair/quad-aligned for DPP)
    const int ch = u >> 1, pp = u & 1;   // channel ch: msg partial pp, blend
                                         // slice pp, tau(pp=0)/mem(pp=1)
    const int k1 = u >> 2, r4 = u & 3;   // h1: 4 lanes/out, K=32 each
    const int oc = u >> 2, orr = u & 3;  // out-proj: 4 lanes/out, K=32 each

    // ---- weights -> f16-packed registers ----
    f16x2 wmh[48];                       // msg: K-slice [pp*96, pp*96+96)
#pragma unroll
    for (int j = 0; j < 48; ++j)
        wmh[j] = mkh2(Wm[(pp * 96 + 2 * j) * HIDDEN + ch],
                      Wm[(pp * 96 + 2 * j + 1) * HIDDEN + ch]);
    f16x2 w1h[16];                       // h1: K-slice [r4*32, +32)
#pragma unroll
    for (int j = 0; j < 16; ++j)
        w1h[j] = mkh2(W1[(r4 * 32 + 2 * j) * HALF + k1],
                      W1[(r4 * 32 + 2 * j + 1) * HALF + k1]);
    const int c2 = pp * 128 + ch;        // pp=0: tau[ch], pp=1: mem[ch]
    f16x2 w2h[32];                       // K=64, no cross-lane reduce
#pragma unroll
    for (int j = 0; j < 32; ++j)
        w2h[j] = mkh2(W2[(2 * j) * (2 * HIDDEN) + c2],
                      W2[(2 * j + 1) * (2 * HIDDEN) + c2]);
    f16x2 woh[16];                       // out: K-slice [orr*32, +32)
#pragma unroll
    for (int j = 0; j < 16; ++j)
        woh[j] = mkh2(Wo[(orr * 32 + 2 * j) * OUT + oc],
                      Wo[(orr * 32 + 2 * j + 1) * OUT + oc]);
    const float bm_r = bm[ch];
    const float b1_r = b1[k1];
    const float b2_r = b2[c2];
    const float bo_r = bo[oc];

    // delay-buffer slice: channel ch, delays pp*64 .. pp*64+63 (fp32)
    float buf[64];
#pragma unroll
    for (int d = 0; d < 64; ++d) buf[d] = 0.f;

    __shared__ float    s_x[2][T * INPUT];        // 64 KB staged inputs (fp32)
    __shared__ _Float16 s_vh[2][INPUT + HIDDEN];  // [x_t | heads], f16
    __shared__ _Float16 s_mh[2][HIDDEN];          // msg, f16
    __shared__ _Float16 s_hh[2][HALF];            // h1, f16

    for (int idx = u; idx < T * INPUT; idx += 256)
        s_x[half][idx] = x[b * T * INPUT + idx];
    if (u < INPUT) s_vh[half][u] = (_Float16)((0 < len) ? x[b * T * INPUT + u] : 0.f);
    else if (u < INPUT + HIDDEN) s_vh[half][u] = (_Float16)0.f;   // heads = 0
    __syncthreads();                                              // B1 (iter 0)

    const float ivb = pp ? 0.5f : 0.f;

    for (int i = 0; i < tmax; ++i) {
        // ---- Phase A: msg[ch] = tanh(v . Wm + bm), pair-reduced ----
        const f16x2* v2 = (const f16x2*)(s_vh[half] + pp * 96);
        float p = dot_h2<48>(wmh, v2);
        p += dpp_movf<DPP_XOR1>(p);                 // both lanes: full dot
        const float z   = p + bm_r;
        const float e2  = __expf(2.f * z);
        const float msg = 1.f - 2.f * __builtin_amdgcn_rcpf(e2 + 1.f);  // tanh
        if (pp == 0) s_mh[half][ch] = (_Float16)msg;
        __syncthreads();                            // B2

        // ---- Phase B: h1[k1] = relu(msg . W1 + b1); stage next x ----
        const f16x2* m2 = (const f16x2*)(s_mh[half] + r4 * 32);
        float p1 = dot_h2<16>(w1h, m2);
        p1 += dpp_movf<DPP_XOR1>(p1);
        p1 += dpp_movf<DPP_XOR2>(p1);               // quad allreduce
        if (r4 == 0) s_hh[half][k1] = (_Float16)fmaxf(p1 + b1_r, 0.f);
        if (u < INPUT) {
            const int nx = i + 1;
            s_vh[half][u] = (_Float16)((nx < len) ? s_x[half][nx * INPUT + u] : 0.f);
        }
        __syncthreads();                            // B3

        // ---- Phase C: tau/mem (1 out/thread, K=64); blend; head; out ----
        const f16x2* h2 = (const f16x2*)s_hh[half];
        const float pt  = dot_h2<32>(w2h, h2);
        const float own = __builtin_amdgcn_rcpf(1.f + __expf(-(pt + b2_r)));
        const float oth = dpp_movf<DPP_XOR1>(own);  // swap tau<->mem in pair
        const float tau_r = pp ? oth : own;
        const float mem_r = pp ? own : oth;

        // blend: channel ch, delays pp*64+d (shift left, interpolate msg)
        {
            const float old64 = dpp_movf<DPP_XOR1>(buf[0]); // partner's old head
            const float tail  = pp ? 0.f : old64;  // pp0 d=63 <- old delay 64
            const float taup  = tau_r - ivb;
            const f32x2 tau2  = splat2(taup);
            const f32x2 mem2  = splat2(mem_r);
            const f32x2 m2m   = splat2(-2.f * mem_r);
            const f32x2 msg2  = splat2(msg);
#pragma unroll
            for (int mp = 0; mp < 32; ++mp) {
                const int d = 2 * mp;
                f32x2 nb;
                nb.x = buf[d + 1];
                nb.y = (mp < 31) ? buf[d + 2] : tail;
                f32x2 t;
                t.x = tau2.x - (float)d       * (1.f / MAX_DELAY);
                t.y = tau2.y - (float)(d + 1) * (1.f / MAX_DELAY);
                f32x2 a  = __builtin_elementwise_max(t, -t);
                f32x2 f1 = a * mem2 + m2m;
                f32x2 iw = a * f1 + mem2;           // mem*(1-a)^2
                f32x2 nv = iw * (msg2 - nb) + nb;
                buf[d] = nv.x; buf[d + 1] = nv.y;
            }
        }
        if (pp == 0) s_vh[half][INPUT + ch] = (_Float16)buf[0];  // next head

        // decode out-projection (guarded to this half's live range)
        if (i >= len && i < total) {
            const f16x2* mo = (const f16x2*)(s_mh[half] + orr * 32);
            float po = dot_h2<16>(woh, mo);
            po += dpp_movf<DPP_XOR1>(po);
            po += dpp_movf<DPP_XOR2>(po);
            if (orr == 0) out[(b * OUT_LEN + (i - len)) * OUT + oc] = po + bo_r;
        }
        __syncthreads();                            // B1 (next iter)
    }
}

extern "C" void kernel_launch(void* const* d_in, const int* in_sizes, int n_in,
                              void* d_out, int out_size, void* d_ws, size_t ws_size,
                              hipStream_t stream) {
    const float* x       = (const float*)d_in[0];
    const int*   lengths = (const int*)  d_in[1];
    // d_in[2] = out_lengths scalar (compile-time 64)
    const float* Wm = (const float*)d_in[3];
    const float* bm = (const float*)d_in[4];
    const float* W1 = (const float*)d_in[5];
    const float* b1 = (const float*)d_in[6];
    const float* W2 = (const float*)d_in[7];
    const float* b2 = (const float*)d_in[8];
    const float* Wo = (const float*)d_in[9];
    const float* bo = (const float*)d_in[10];
    float* out = (float*)d_out;

    delayrnn_kernel<<<BATCH / 2, NTHR, 0, stream>>>(
        x, lengths, Wm, bm, W1, b1, W2, b2, Wo, bo, out);
}